// Round 25
// baseline (178.810 us; speedup 1.0000x reference)
//
#include <hip/hip_runtime.h>
#include <math.h>

#define BB   32
#define HH   56
#define WWI  56
#define CC   96
#define NHD  3
#define WSZ  7
#define SHF  3
#define NTK  49
#define NWIN 64
#define HDM  32
#define TOT  (BB*HH*WWI)               // 100352
#define QKSCALE 0.17677669529663687f
#define LEPS 1e-3f

typedef __attribute__((ext_vector_type(8))) short s8v;    // 8 bf16 (4 VGPRs)
typedef __attribute__((ext_vector_type(4))) float fx4;    // 4 fp32
typedef __attribute__((ext_vector_type(16))) float fx16;  // 16 fp32
typedef unsigned long long ull_t;

#define MFMA16(a,b,c) __builtin_amdgcn_mfma_f32_16x16x32_bf16((a),(b),(c),0,0,0)
#define MFMA32(a,b,c) __builtin_amdgcn_mfma_f32_32x32x16_bf16((a),(b),(c),0,0,0)

__device__ __forceinline__ unsigned short f2bf(float f) {
    union { float f; unsigned u; } v; v.f = f;
    unsigned r = v.u + 0x7FFFu + ((v.u >> 16) & 1u);
    return (unsigned short)(r >> 16);
}
__device__ __forceinline__ float bf2f(unsigned short u) {
    return __uint_as_float((unsigned)u << 16);
}

// sigmoid-form gelu, op-minimized (R21)
__device__ __forceinline__ float gelu_t(float x) {
    float x2 = x * x;
#if __has_builtin(__builtin_amdgcn_exp2f)
    float z = x * fmaf(-0.10294326f, x2, -2.3022082f);   // -log2(e)*1.59577*(1, .044715)
    float e = __builtin_amdgcn_exp2f(z);
#else
    float z = x * fmaf(-0.07135529f, x2, -1.5957691f);
    float e = __expf(z);
#endif
    return x * __builtin_amdgcn_rcpf(1.f + e);
}

// windowed token id -> original flat token id (roll(-3,-3) + window partition)
__device__ __forceinline__ int wtok_to_orig(int wt) {
    int win = wt / NTK;
    int p   = wt - win * NTK;
    int b   = win >> 6;
    int w   = win & 63;
    int wi = w >> 3, wj = w & 7;
    int pi = p / WSZ, pj = p - pi * WSZ;
    int r = wi * WSZ + pi + SHF; if (r >= HH) r -= HH;
    int c = wj * WSZ + pj + SHF; if (c >= WWI) c -= WWI;
    return b * (HH * WWI) + r * WWI + c;
}

// LayerNorm in 16x16 MFMA-A-fragment layout (k12 uses this)
__device__ __forceinline__ void ln_frag(const float* __restrict__ row,
                                        const float* __restrict__ gg,
                                        const float* __restrict__ bb,
                                        int g4, s8v ha[3])
{
    float h[24];
    #pragma unroll
    for (int ks = 0; ks < 3; ++ks) {
        fx4 v0 = *reinterpret_cast<const fx4*>(row + ks * 32 + g4 * 8);
        fx4 v1 = *reinterpret_cast<const fx4*>(row + ks * 32 + g4 * 8 + 4);
        h[ks*8+0]=v0.x; h[ks*8+1]=v0.y; h[ks*8+2]=v0.z; h[ks*8+3]=v0.w;
        h[ks*8+4]=v1.x; h[ks*8+5]=v1.y; h[ks*8+6]=v1.z; h[ks*8+7]=v1.w;
    }
    float s = 0.f, s2 = 0.f;
    #pragma unroll
    for (int j = 0; j < 24; ++j) { s += h[j]; s2 = fmaf(h[j], h[j], s2); }
    s  += __shfl_xor(s, 16);  s  += __shfl_xor(s, 32);
    s2 += __shfl_xor(s2, 16); s2 += __shfl_xor(s2, 32);
    const float mu = s * (1.f/CC);
    const float rs = rsqrtf(s2 * (1.f/CC) - mu * mu + LEPS);
    #pragma unroll
    for (int ks = 0; ks < 3; ++ks) {
        union { s8v v; unsigned short u[8]; } p;
        #pragma unroll
        for (int j = 0; j < 8; ++j) {
            int c = ks * 32 + g4 * 8 + j;
            p.u[j] = f2bf((h[ks*8+j] - mu) * rs * gg[c] + bb[c]);
        }
        ha[ks] = p.v;
    }
}

// ---------- P0: qwtf 16x16-frag (k12) | pwtf/w1f/w2f 32x32-frag (k23) | bmf ----------
extern "C" __global__ void p0_prep(const float* __restrict__ qw, const float* __restrict__ pw,
                                   const float* __restrict__ w1, const float* __restrict__ w2,
                                   const float* __restrict__ btab,
                                   unsigned short* __restrict__ wsw)
{
    int i = blockIdx.x * 256 + threadIdx.x;
    if (i < 27648) {                       // qwtf 16x16 frag-linear (unchanged)
        int e = i & 7, f = i >> 3;
        int lane = f & 63, fid = f >> 6;   // fid 0..53
        int ks = fid % 3, t = fid / 3;
        int nt = t % 6, ck = t / 6;
        int n = ck * 96 + nt * 16 + (lane & 15);
        int k = ks * 32 + (lane >> 4) * 8 + e;
        float v = qw[k * 288 + n];
        if (n < 96) v *= QKSCALE;
        wsw[i] = f2bf(v);
    } else if (i < 36864) {                // pwtf 32x32 frag-linear: fid = nt*6+ks
        int j = i - 27648;
        int e = j & 7, f = j >> 3;
        int lane = f & 63, fid = f >> 6;   // fid 0..17
        int ks = fid % 6, nt = fid / 6;
        int n = nt * 32 + (lane & 31);
        int k = ks * 16 + (lane >> 5) * 8 + e;
        wsw[i] = f2bf(pw[k * 96 + n]);
    } else if (i < 73728) {                // w1f 32x32 frag-linear: fid = (ck*2+nt)*6+ks
        int j = i - 36864;
        int e = j & 7, f = j >> 3;
        int lane = f & 63, fid = f >> 6;   // fid 0..71
        int ks = fid % 6, t = fid / 6;
        int nt = t & 1, ck = t >> 1;
        int n = ck * 64 + nt * 32 + (lane & 31);
        int k = ks * 16 + (lane >> 5) * 8 + e;
        wsw[i] = f2bf(w1[k * 384 + n]);
    } else if (i < 110592) {               // w2f 32x32 frag-linear: fid = (ck*3+nt)*4+ks
        int j = i - 73728;
        int e = j & 7, f = j >> 3;
        int lane = f & 63, fid = f >> 6;   // fid 0..71
        int ks = fid & 3, t = fid >> 2;
        int nt = t % 3, ck = t / 3;
        int n = nt * 32 + (lane & 31);
        int k = ck * 64 + ks * 16 + (lane >> 5) * 8 + e;
        wsw[i] = f2bf(w2[k * 96 + n]);
    } else if (i < 159744) {               // bmf: BM in 16x16 D-frag layout (fp32)
        float* bmf = (float*)(wsw + 110592);
        int j = i - 110592;                // 0..49151
        int r = j & 3, lane = (j >> 2) & 63;
        int fid = j >> 8;                  // 0..191
        int mtnt = fid & 15, t = fid >> 4; // t 0..11
        int mt = mtnt >> 2, nt = mtnt & 3;
        int hd = t % 3, cls = t / 3;
        int m = mt * 16 + (lane >> 4) * 4 + r; if (m > 48) m = 48;
        int n = nt * 16 + (lane & 15);
        float val = 0.f;
        if (n < 49) {
            int it = m / 7, jt = m - it * 7;
            int iu = n / 7, ju = n - iu * 7;
            int li  = (cls & 2) ? (it < 4 ? 1 : 2) : 0;
            int lj  = (cls & 1) ? (jt < 4 ? 1 : 2) : 0;
            int lui = (cls & 2) ? (iu < 4 ? 1 : 2) : 0;
            int luj = (cls & 1) ? (ju < 4 ? 1 : 2) : 0;
            int bidx = (jt - ju + 6) * 13 + (it - iu + 6);
            val = btab[bidx * 3 + hd] + ((li*3+lj) == (lui*3+luj) ? 0.f : -100.f);
        }
        bmf[j] = val;
    }
}

// ---------- K12: fused LN1 + QKV GEMM + attention; block = 1 window (R23 form) ----------
#define LDQ 104
extern "C" __global__ void __launch_bounds__(256, 2) k12_fused(
    const float* __restrict__ x, const float* __restrict__ g1, const float* __restrict__ b1,
    const unsigned short* __restrict__ qwtf, const float* __restrict__ qb,
    const float* __restrict__ bmf, unsigned short* __restrict__ ovb)
{
    __shared__ unsigned short Qs[64 * LDQ];    // 13312 B
    __shared__ unsigned short Ks[64 * LDQ];    // 13312 B
    __shared__ unsigned short P[3][64 * 72];   // 27648 B  (total 54272)
    const int tid = threadIdx.x, wave = tid >> 6, lane = tid & 63;
    const int l15 = lane & 15, g4 = lane >> 4;
    const int win = blockIdx.x;
    const int g0  = win * NTK;

    s8v ha[3];
    {
        int row = wave * 16 + l15;
        int tok = row > 48 ? 48 : row;
        ln_frag(x + (size_t)wtok_to_orig(g0 + tok) * CC, g1, b1, g4, ha);
    }

    #pragma unroll
    for (int ck = 0; ck < 3; ++ck) {
        fx4 acc[6];
        #pragma unroll
        for (int nt = 0; nt < 6; ++nt) acc[nt] = (fx4){0.f,0.f,0.f,0.f};
        #pragma unroll
        for (int ks = 0; ks < 3; ++ks) {
            #pragma unroll
            for (int nt = 0; nt < 6; ++nt) {
                s8v b = *reinterpret_cast<const s8v*>(
                    &qwtf[(((ck * 6 + nt) * 3 + ks) * 64 + lane) * 8]);
                acc[nt] = MFMA16(ha[ks], b, acc[nt]);
            }
        }
        const int rowb = wave * 16 + g4 * 4;
        if (ck == 0) {
            #pragma unroll
            for (int nt = 0; nt < 6; ++nt) {
                const int col = nt * 16 + l15;
                const float qbc = qb[col] * QKSCALE;
                #pragma unroll
                for (int r = 0; r < 4; ++r)
                    Qs[(rowb + r) * LDQ + col] = f2bf(acc[nt][r] + qbc);
            }
        } else if (ck == 1) {
            #pragma unroll
            for (int nt = 0; nt < 6; ++nt) {
                const int col = nt * 16 + l15;
                const float qbc = qb[96 + col];
                #pragma unroll
                for (int r = 0; r < 4; ++r)
                    Ks[(rowb + r) * LDQ + col] = f2bf(acc[nt][r] + qbc);
            }
        } else {
            #pragma unroll
            for (int nt = 0; nt < 6; ++nt) {
                const int col = nt * 16 + l15;
                const float qbc = qb[192 + col];
                #pragma unroll
                for (int r = 0; r < 4; ++r) {
                    const int rr = rowb + r;
                    if (rr < NTK)
                        ovb[(size_t)(g0 + rr) * 96 + col] = f2bf(acc[nt][r] + qbc);
                }
            }
        }
    }
    __syncthreads();

    if (wave < 3) {
        const int h = wave;
        const int w = win & 63;
        const int cls = (((w >> 3) == 7) ? 2 : 0) + (((w & 7) == 7) ? 1 : 0);
        const float* BMF = bmf + (size_t)(cls * 3 + h) * 4096;
        unsigned short* Ph = &P[h][0];

        s8v aq[4], bk[4];
        #pragma unroll
        for (int mt = 0; mt < 4; ++mt) {
            const int rm = mt * 16 + l15;
            aq[mt] = *reinterpret_cast<const s8v*>(&Qs[rm * LDQ + h * 32 + g4 * 8]);
            bk[mt] = *reinterpret_cast<const s8v*>(&Ks[rm * LDQ + h * 32 + g4 * 8]);
        }

        fx4 sc[4][4];
        #pragma unroll
        for (int mt = 0; mt < 4; ++mt)
            #pragma unroll
            for (int nt = 0; nt < 4; ++nt)
                sc[mt][nt] = MFMA16(aq[mt], bk[nt], ((fx4){0.f,0.f,0.f,0.f}));

        #pragma unroll
        for (int mt = 0; mt < 4; ++mt) {
            fx4 bmv[4];
            #pragma unroll
            for (int nt = 0; nt < 4; ++nt)
                bmv[nt] = *reinterpret_cast<const fx4*>(&BMF[((mt * 4 + nt) << 8) + lane * 4]);
            #pragma unroll
            for (int r = 0; r < 4; ++r) {
                float rs1 = 0.f;
                #pragma unroll
                for (int nt = 0; nt < 4; ++nt) {
                    const int n = nt * 16 + l15;
                    float s = sc[mt][nt][r] + bmv[nt][r];
                    float e = (n < NTK) ? __expf(s) : 0.f;
                    sc[mt][nt][r] = e;
                    rs1 += e;
                }
                rs1 += __shfl_xor(rs1, 1); rs1 += __shfl_xor(rs1, 2);
                rs1 += __shfl_xor(rs1, 4); rs1 += __shfl_xor(rs1, 8);
                const float iv1 = 1.f / rs1;
                float rs2 = 0.f;
                #pragma unroll
                for (int nt = 0; nt < 4; ++nt) {
                    const int n = nt * 16 + l15;
                    float e2 = (n < NTK) ? __expf(sc[mt][nt][r] * iv1) : 0.f;
                    sc[mt][nt][r] = e2;
                    rs2 += e2;
                }
                rs2 += __shfl_xor(rs2, 1); rs2 += __shfl_xor(rs2, 2);
                rs2 += __shfl_xor(rs2, 4); rs2 += __shfl_xor(rs2, 8);
                const float iv2 = 1.f / rs2;
                const int m = mt * 16 + g4 * 4 + r;
                #pragma unroll
                for (int nt = 0; nt < 4; ++nt)
                    Ph[m * 72 + nt * 16 + l15] = f2bf(sc[mt][nt][r] * iv2);
            }
        }

        fx4 oc[4][2];
        #pragma unroll
        for (int mt = 0; mt < 4; ++mt) { oc[mt][0] = (fx4){0.f,0.f,0.f,0.f}; oc[mt][1] = (fx4){0.f,0.f,0.f,0.f}; }
        #pragma unroll
        for (int ks = 0; ks < 2; ++ks) {
            s8v vb[2];
            #pragma unroll
            for (int nt = 0; nt < 2; ++nt) {
                union { s8v v; unsigned short u[8]; } pv;
                #pragma unroll
                for (int j = 0; j < 8; ++j) {
                    int tok = ks * 32 + g4 * 8 + j; if (tok > 48) tok = 48;
                    pv.u[j] = ovb[(size_t)(g0 + tok) * 96 + h * 32 + nt * 16 + l15];
                }
                vb[nt] = pv.v;
            }
            #pragma unroll
            for (int mt = 0; mt < 4; ++mt) {
                s8v pa = *reinterpret_cast<const s8v*>(&Ph[(mt * 16 + l15) * 72 + ks * 32 + g4 * 8]);
                oc[mt][0] = MFMA16(pa, vb[0], oc[mt][0]);
                oc[mt][1] = MFMA16(pa, vb[1], oc[mt][1]);
            }
        }
        #pragma unroll
        for (int mt = 0; mt < 4; ++mt) {
            #pragma unroll
            for (int r = 0; r < 4; ++r) {
                const int m = mt * 16 + g4 * 4 + r;
                if (m < NTK) {
                    ovb[(size_t)(g0 + m) * 96 + h * 32 + l15]      = f2bf(oc[mt][0][r]);
                    ovb[(size_t)(g0 + m) * 96 + h * 32 + 16 + l15] = f2bf(oc[mt][1][r]);
                }
            }
        }
    }
}

// ---------- K23: fused proj + residual + LN2 + MLP + residual, 32x32 MFMA ----------
// One wave owns 32 tokens: weight bytes AND MFMA instructions per token halve
// vs the 16x16 version, same single-accumulator structure. X2 held bf16 in LDS
// (43KB total -> 3 blocks/CU). D-layout: col=lane&31, row=(r&3)+8*(r>>2)+4*(lane>>5).
#define LDX2B 104
extern "C" __global__ void __launch_bounds__(256, 3) k23_fused(
    const unsigned short* __restrict__ ovb, const unsigned short* __restrict__ pwtf,
    const float* __restrict__ pb, const float* __restrict__ x,
    const float* __restrict__ g2, const float* __restrict__ b2,
    const unsigned short* __restrict__ w1f, const float* __restrict__ bf1,
    const unsigned short* __restrict__ w2f, const float* __restrict__ bf2,
    float* __restrict__ out)
{
    __shared__ unsigned short X2b[128 * LDX2B];  // 26624 B, wave-private rows
    __shared__ unsigned short Ac[128 * 64];      // 16384 B  (total 43008)
    const int tid = threadIdx.x, wave = tid >> 6, lane = tid & 63;
    const int l31 = lane & 31, gk = lane >> 5;
    const int row0 = blockIdx.x * 128 + wave * 32;   // orig-token rows

    // ---- proj (32x32): A-frags gathered from ovb via inverse shift map ----
    s8v a[6];
    {
        const int t = row0 + l31;
        const int b = t / (HH * WWI), rc = t - b * (HH * WWI);
        const int orr = rc / WWI, occ = rc - orr * WWI;
        int wr = orr + (HH - SHF); if (wr >= HH) wr -= HH;
        int wc = occ + (WWI - SHF); if (wc >= WWI) wc -= WWI;
        const int wtok = (b * 64 + (wr / WSZ) * 8 + (wc / WSZ)) * NTK
                         + (wr % WSZ) * WSZ + (wc % WSZ);
        const unsigned short* arow = ovb + (size_t)wtok * 96 + gk * 8;
        #pragma unroll
        for (int ks = 0; ks < 6; ++ks)
            a[ks] = *reinterpret_cast<const s8v*>(arow + ks * 16);
    }
    {
        fx16 acc[3];
        #pragma unroll
        for (int nt = 0; nt < 3; ++nt) acc[nt] = (fx16)(0.f);
        #pragma unroll
        for (int ks = 0; ks < 6; ++ks) {
            #pragma unroll
            for (int nt = 0; nt < 3; ++nt) {
                s8v b = *reinterpret_cast<const s8v*>(&pwtf[((nt * 6 + ks) * 64 + lane) * 8]);
                acc[nt] = MFMA32(a[ks], b, acc[nt]);
            }
        }
        // x2 = proj + pb + x -> LDS bf16 (D-layout indexing; x read linear-ish)
        #pragma unroll
        for (int nt = 0; nt < 3; ++nt) {
            const int col = nt * 32 + l31;
            const float pbc = pb[col];
            #pragma unroll
            for (int r = 0; r < 16; ++r) {
                const int drow = (r & 3) + 8 * (r >> 2) + 4 * gk;
                X2b[(wave * 32 + drow) * LDX2B + col] =
                    f2bf(acc[nt][r] + pbc + x[(size_t)(row0 + drow) * CC + col]);
            }
        }
    }

    // ---- LN2 from bf16 LDS (wave-private; 2 lanes share a row, xor-32 reduce) ----
    s8v ha[6];
    {
        const unsigned short* xr = &X2b[(wave * 32 + l31) * LDX2B + gk * 8];
        float h[48];
        float s = 0.f, s2 = 0.f;
        #pragma unroll
        for (int ks = 0; ks < 6; ++ks) {
            #pragma unroll
            for (int j = 0; j < 8; ++j) {
                float v = bf2f(xr[ks * 16 + j]);
                h[ks * 8 + j] = v;
                s += v; s2 = fmaf(v, v, s2);
            }
        }
        s += __shfl_xor(s, 32); s2 += __shfl_xor(s2, 32);
        const float mu = s * (1.f/CC);
        const float rs = rsqrtf(s2 * (1.f/CC) - mu * mu + LEPS);
        #pragma unroll
        for (int ks = 0; ks < 6; ++ks) {
            union { s8v v; unsigned short u[8]; } p;
            #pragma unroll
            for (int j = 0; j < 8; ++j) {
                int c = ks * 16 + gk * 8 + j;
                p.u[j] = f2bf((h[ks * 8 + j] - mu) * rs * g2[c] + b2[c]);
            }
            ha[ks] = p.v;
        }
    }

    fx16 oacc[3];
    #pragma unroll
    for (int nt = 0; nt < 3; ++nt) oacc[nt] = (fx16)(0.f);

    #pragma unroll 1
    for (int ck = 0; ck < 6; ++ck) {
        // fc1 (32x32): M=32 tok, N=64 (2 nt), K=96 (6 ks)
        fx16 a1[2];
        a1[0] = (fx16)(0.f); a1[1] = (fx16)(0.f);
        #pragma unroll
        for (int ks = 0; ks < 6; ++ks) {
            #pragma unroll
            for (int nt = 0; nt < 2; ++nt) {
                s8v b = *reinterpret_cast<const s8v*>(
                    &w1f[((((ck * 2 + nt) * 6) + ks) * 64 + lane) * 8]);
                a1[nt] = MFMA32(ha[ks], b, a1[nt]);
            }
        }
        // gelu^2 -> Ac (wave-private rows; in-wave lgkmcnt ordering)
        #pragma unroll
        for (int nt = 0; nt < 2; ++nt) {
            const float bb = bf1[ck * 64 + nt * 32 + l31];
            #pragma unroll
            for (int r = 0; r < 16; ++r) {
                const int drow = (r & 3) + 8 * (r >> 2) + 4 * gk;
                Ac[(wave * 32 + drow) * 64 + nt * 32 + l31] =
                    f2bf(gelu_t(gelu_t(a1[nt][r] + bb)));
            }
        }
        // fc2 (32x32): M=32 tok, N=96 (3 nt), K=64 (4 ks)
        #pragma unroll
        for (int ks = 0; ks < 4; ++ks) {
            s8v aa = *reinterpret_cast<const s8v*>(
                &Ac[(wave * 32 + l31) * 64 + ks * 16 + gk * 8]);
            #pragma unroll
            for (int nt = 0; nt < 3; ++nt) {
                s8v b = *reinterpret_cast<const s8v*>(
                    &w2f[((((ck * 3 + nt) * 4) + ks) * 64 + lane) * 8]);
                oacc[nt] = MFMA32(aa, b, oacc[nt]);
            }
        }
    }

    // ---- final: out = x2 + mlp + bf2 ----
    #pragma unroll
    for (int nt = 0; nt < 3; ++nt) {
        const int col = nt * 32 + l31;
        const float bb = bf2[col];
        #pragma unroll
        for (int r = 0; r < 16; ++r) {
            const int drow = (r & 3) + 8 * (r >> 2) + 4 * gk;
            out[(size_t)(row0 + drow) * CC + col] =
                bf2f(X2b[(wave * 32 + drow) * LDX2B + col]) + oacc[nt][r] + bb;
        }
    }
}

extern "C" void kernel_launch(void* const* d_in, const int* in_sizes, int n_in,
                              void* d_out, int out_size, void* d_ws, size_t ws_size,
                              hipStream_t stream)
{
    const float* x    = (const float*)d_in[0];
    const float* n1g  = (const float*)d_in[1];
    const float* n1b  = (const float*)d_in[2];
    const float* qw   = (const float*)d_in[3];
    const float* qb   = (const float*)d_in[4];
    const float* btab = (const float*)d_in[5];
    const float* pw   = (const float*)d_in[6];
    const float* pb   = (const float*)d_in[7];
    const float* n2g  = (const float*)d_in[8];
    const float* n2b  = (const float*)d_in[9];
    const float* w1   = (const float*)d_in[10];
    const float* bf1  = (const float*)d_in[11];
    const float* w2   = (const float*)d_in[12];
    const float* bf2  = (const float*)d_in[13];
    float* out = (float*)d_out;

    unsigned short* ovb  = (unsigned short*)d_ws;                 // TOT*96 bf16 = 19.3 MB (V then O)
    unsigned short* wbf  = ovb + (size_t)TOT * 96;
    unsigned short* qwtf = wbf;                                   // 27648 (16x16 frag)
    unsigned short* pwtf = qwtf + 27648;                          // 9216  (32x32 frag)
    unsigned short* w1f  = pwtf + 9216;                           // 36864 (32x32 frag)
    unsigned short* w2f  = w1f + 36864;                           // 36864 (32x32 frag)
    float* bmf = (float*)(wbf + 110592);                          // 49152 fp32 (D-frag)

    p0_prep  <<<624, 256, 0, stream>>>(qw, pw, w1, w2, btab, wbf);
    k12_fused<<<BB*NWIN, 256, 0, stream>>>(x, n1g, n1b, qwtf, qb, bmf, ovb);
    k23_fused<<<TOT/128, 256, 0, stream>>>(ovb, pwtf, pb, x, n2g, n2b,
                                           w1f, bf1, w2f, bf2, out);
}

// Round 26
// 178.400 us; speedup vs baseline: 1.0023x; 1.0023x over previous
//
#include <hip/hip_runtime.h>
#include <math.h>

#define BB   32
#define HH   56
#define WWI  56
#define CC   96
#define NHD  3
#define WSZ  7
#define SHF  3
#define NTK  49
#define NWIN 64
#define HDM  32
#define TOT  (BB*HH*WWI)               // 100352
#define QKSCALE 0.17677669529663687f
#define LEPS 1e-3f

typedef __attribute__((ext_vector_type(8))) short s8v;    // 8 bf16 (4 VGPRs)
typedef __attribute__((ext_vector_type(4))) float fx4;    // 4 fp32
typedef __attribute__((ext_vector_type(16))) float fx16;  // 16 fp32
typedef unsigned long long ull_t;

#define MFMA16(a,b,c) __builtin_amdgcn_mfma_f32_16x16x32_bf16((a),(b),(c),0,0,0)
#define MFMA32(a,b,c) __builtin_amdgcn_mfma_f32_32x32x16_bf16((a),(b),(c),0,0,0)

__device__ __forceinline__ unsigned short f2bf(float f) {
    union { float f; unsigned u; } v; v.f = f;
    unsigned r = v.u + 0x7FFFu + ((v.u >> 16) & 1u);
    return (unsigned short)(r >> 16);
}
__device__ __forceinline__ float bf2f(unsigned short u) {
    return __uint_as_float((unsigned)u << 16);
}

// sigmoid-form gelu, op-minimized (R21)
__device__ __forceinline__ float gelu_t(float x) {
    float x2 = x * x;
#if __has_builtin(__builtin_amdgcn_exp2f)
    float z = x * fmaf(-0.10294326f, x2, -2.3022082f);   // -log2(e)*1.59577*(1, .044715)
    float e = __builtin_amdgcn_exp2f(z);
#else
    float z = x * fmaf(-0.07135529f, x2, -1.5957691f);
    float e = __expf(z);
#endif
    return x * __builtin_amdgcn_rcpf(1.f + e);
}

// windowed token id -> original flat token id (roll(-3,-3) + window partition)
__device__ __forceinline__ int wtok_to_orig(int wt) {
    int win = wt / NTK;
    int p   = wt - win * NTK;
    int b   = win >> 6;
    int w   = win & 63;
    int wi = w >> 3, wj = w & 7;
    int pi = p / WSZ, pj = p - pi * WSZ;
    int r = wi * WSZ + pi + SHF; if (r >= HH) r -= HH;
    int c = wj * WSZ + pj + SHF; if (c >= WWI) c -= WWI;
    return b * (HH * WWI) + r * WWI + c;
}

// LayerNorm in 16x16 MFMA-A-fragment layout (k12 uses this)
__device__ __forceinline__ void ln_frag(const float* __restrict__ row,
                                        const float* __restrict__ gg,
                                        const float* __restrict__ bb,
                                        int g4, s8v ha[3])
{
    float h[24];
    #pragma unroll
    for (int ks = 0; ks < 3; ++ks) {
        fx4 v0 = *reinterpret_cast<const fx4*>(row + ks * 32 + g4 * 8);
        fx4 v1 = *reinterpret_cast<const fx4*>(row + ks * 32 + g4 * 8 + 4);
        h[ks*8+0]=v0.x; h[ks*8+1]=v0.y; h[ks*8+2]=v0.z; h[ks*8+3]=v0.w;
        h[ks*8+4]=v1.x; h[ks*8+5]=v1.y; h[ks*8+6]=v1.z; h[ks*8+7]=v1.w;
    }
    float s = 0.f, s2 = 0.f;
    #pragma unroll
    for (int j = 0; j < 24; ++j) { s += h[j]; s2 = fmaf(h[j], h[j], s2); }
    s  += __shfl_xor(s, 16);  s  += __shfl_xor(s, 32);
    s2 += __shfl_xor(s2, 16); s2 += __shfl_xor(s2, 32);
    const float mu = s * (1.f/CC);
    const float rs = rsqrtf(s2 * (1.f/CC) - mu * mu + LEPS);
    #pragma unroll
    for (int ks = 0; ks < 3; ++ks) {
        union { s8v v; unsigned short u[8]; } p;
        #pragma unroll
        for (int j = 0; j < 8; ++j) {
            int c = ks * 32 + g4 * 8 + j;
            p.u[j] = f2bf((h[ks*8+j] - mu) * rs * gg[c] + bb[c]);
        }
        ha[ks] = p.v;
    }
}

// ---------- P0: qwtf 16x16-frag (k12) | pwtf/w1f/w2f 32x32-frag (k23) | bmf ----------
extern "C" __global__ void p0_prep(const float* __restrict__ qw, const float* __restrict__ pw,
                                   const float* __restrict__ w1, const float* __restrict__ w2,
                                   const float* __restrict__ btab,
                                   unsigned short* __restrict__ wsw)
{
    int i = blockIdx.x * 256 + threadIdx.x;
    if (i < 27648) {                       // qwtf 16x16 frag-linear (unchanged)
        int e = i & 7, f = i >> 3;
        int lane = f & 63, fid = f >> 6;   // fid 0..53
        int ks = fid % 3, t = fid / 3;
        int nt = t % 6, ck = t / 6;
        int n = ck * 96 + nt * 16 + (lane & 15);
        int k = ks * 32 + (lane >> 4) * 8 + e;
        float v = qw[k * 288 + n];
        if (n < 96) v *= QKSCALE;
        wsw[i] = f2bf(v);
    } else if (i < 36864) {                // pwtf 32x32 frag-linear: fid = nt*6+ks
        int j = i - 27648;
        int e = j & 7, f = j >> 3;
        int lane = f & 63, fid = f >> 6;   // fid 0..17
        int ks = fid % 6, nt = fid / 6;
        int n = nt * 32 + (lane & 31);
        int k = ks * 16 + (lane >> 5) * 8 + e;
        wsw[i] = f2bf(pw[k * 96 + n]);
    } else if (i < 73728) {                // w1f 32x32 frag-linear: fid = (ck*2+nt)*6+ks
        int j = i - 36864;
        int e = j & 7, f = j >> 3;
        int lane = f & 63, fid = f >> 6;   // fid 0..71
        int ks = fid % 6, t = fid / 6;
        int nt = t & 1, ck = t >> 1;
        int n = ck * 64 + nt * 32 + (lane & 31);
        int k = ks * 16 + (lane >> 5) * 8 + e;
        wsw[i] = f2bf(w1[k * 384 + n]);
    } else if (i < 110592) {               // w2f 32x32 frag-linear: fid = (ck*3+nt)*4+ks
        int j = i - 73728;
        int e = j & 7, f = j >> 3;
        int lane = f & 63, fid = f >> 6;   // fid 0..71
        int ks = fid & 3, t = fid >> 2;
        int nt = t % 3, ck = t / 3;
        int n = nt * 32 + (lane & 31);
        int k = ck * 64 + ks * 16 + (lane >> 5) * 8 + e;
        wsw[i] = f2bf(w2[k * 96 + n]);
    } else if (i < 159744) {               // bmf: BM in 16x16 D-frag layout (fp32)
        float* bmf = (float*)(wsw + 110592);
        int j = i - 110592;                // 0..49151
        int r = j & 3, lane = (j >> 2) & 63;
        int fid = j >> 8;                  // 0..191
        int mtnt = fid & 15, t = fid >> 4; // t 0..11
        int mt = mtnt >> 2, nt = mtnt & 3;
        int hd = t % 3, cls = t / 3;
        int m = mt * 16 + (lane >> 4) * 4 + r; if (m > 48) m = 48;
        int n = nt * 16 + (lane & 15);
        float val = 0.f;
        if (n < 49) {
            int it = m / 7, jt = m - it * 7;
            int iu = n / 7, ju = n - iu * 7;
            int li  = (cls & 2) ? (it < 4 ? 1 : 2) : 0;
            int lj  = (cls & 1) ? (jt < 4 ? 1 : 2) : 0;
            int lui = (cls & 2) ? (iu < 4 ? 1 : 2) : 0;
            int luj = (cls & 1) ? (ju < 4 ? 1 : 2) : 0;
            int bidx = (jt - ju + 6) * 13 + (it - iu + 6);
            val = btab[bidx * 3 + hd] + ((li*3+lj) == (lui*3+luj) ? 0.f : -100.f);
        }
        bmf[j] = val;
    }
}

// ---------- K12: fused LN1 + QKV GEMM + attention; block = 1 window (R23 form) ----------
#define LDQ 104
extern "C" __global__ void __launch_bounds__(256, 2) k12_fused(
    const float* __restrict__ x, const float* __restrict__ g1, const float* __restrict__ b1,
    const unsigned short* __restrict__ qwtf, const float* __restrict__ qb,
    const float* __restrict__ bmf, unsigned short* __restrict__ ovb)
{
    __shared__ unsigned short Qs[64 * LDQ];    // 13312 B
    __shared__ unsigned short Ks[64 * LDQ];    // 13312 B
    __shared__ unsigned short P[3][64 * 72];   // 27648 B  (total 54272)
    const int tid = threadIdx.x, wave = tid >> 6, lane = tid & 63;
    const int l15 = lane & 15, g4 = lane >> 4;
    const int win = blockIdx.x;
    const int g0  = win * NTK;

    s8v ha[3];
    {
        int row = wave * 16 + l15;
        int tok = row > 48 ? 48 : row;
        ln_frag(x + (size_t)wtok_to_orig(g0 + tok) * CC, g1, b1, g4, ha);
    }

    #pragma unroll
    for (int ck = 0; ck < 3; ++ck) {
        fx4 acc[6];
        #pragma unroll
        for (int nt = 0; nt < 6; ++nt) acc[nt] = (fx4){0.f,0.f,0.f,0.f};
        #pragma unroll
        for (int ks = 0; ks < 3; ++ks) {
            #pragma unroll
            for (int nt = 0; nt < 6; ++nt) {
                s8v b = *reinterpret_cast<const s8v*>(
                    &qwtf[(((ck * 6 + nt) * 3 + ks) * 64 + lane) * 8]);
                acc[nt] = MFMA16(ha[ks], b, acc[nt]);
            }
        }
        const int rowb = wave * 16 + g4 * 4;
        if (ck == 0) {
            #pragma unroll
            for (int nt = 0; nt < 6; ++nt) {
                const int col = nt * 16 + l15;
                const float qbc = qb[col] * QKSCALE;
                #pragma unroll
                for (int r = 0; r < 4; ++r)
                    Qs[(rowb + r) * LDQ + col] = f2bf(acc[nt][r] + qbc);
            }
        } else if (ck == 1) {
            #pragma unroll
            for (int nt = 0; nt < 6; ++nt) {
                const int col = nt * 16 + l15;
                const float qbc = qb[96 + col];
                #pragma unroll
                for (int r = 0; r < 4; ++r)
                    Ks[(rowb + r) * LDQ + col] = f2bf(acc[nt][r] + qbc);
            }
        } else {
            #pragma unroll
            for (int nt = 0; nt < 6; ++nt) {
                const int col = nt * 16 + l15;
                const float qbc = qb[192 + col];
                #pragma unroll
                for (int r = 0; r < 4; ++r) {
                    const int rr = rowb + r;
                    if (rr < NTK)
                        ovb[(size_t)(g0 + rr) * 96 + col] = f2bf(acc[nt][r] + qbc);
                }
            }
        }
    }
    __syncthreads();

    if (wave < 3) {
        const int h = wave;
        const int w = win & 63;
        const int cls = (((w >> 3) == 7) ? 2 : 0) + (((w & 7) == 7) ? 1 : 0);
        const float* BMF = bmf + (size_t)(cls * 3 + h) * 4096;
        unsigned short* Ph = &P[h][0];

        s8v aq[4], bk[4];
        #pragma unroll
        for (int mt = 0; mt < 4; ++mt) {
            const int rm = mt * 16 + l15;
            aq[mt] = *reinterpret_cast<const s8v*>(&Qs[rm * LDQ + h * 32 + g4 * 8]);
            bk[mt] = *reinterpret_cast<const s8v*>(&Ks[rm * LDQ + h * 32 + g4 * 8]);
        }

        fx4 sc[4][4];
        #pragma unroll
        for (int mt = 0; mt < 4; ++mt)
            #pragma unroll
            for (int nt = 0; nt < 4; ++nt)
                sc[mt][nt] = MFMA16(aq[mt], bk[nt], ((fx4){0.f,0.f,0.f,0.f}));

        #pragma unroll
        for (int mt = 0; mt < 4; ++mt) {
            fx4 bmv[4];
            #pragma unroll
            for (int nt = 0; nt < 4; ++nt)
                bmv[nt] = *reinterpret_cast<const fx4*>(&BMF[((mt * 4 + nt) << 8) + lane * 4]);
            #pragma unroll
            for (int r = 0; r < 4; ++r) {
                float rs1 = 0.f;
                #pragma unroll
                for (int nt = 0; nt < 4; ++nt) {
                    const int n = nt * 16 + l15;
                    float s = sc[mt][nt][r] + bmv[nt][r];
                    float e = (n < NTK) ? __expf(s) : 0.f;
                    sc[mt][nt][r] = e;
                    rs1 += e;
                }
                rs1 += __shfl_xor(rs1, 1); rs1 += __shfl_xor(rs1, 2);
                rs1 += __shfl_xor(rs1, 4); rs1 += __shfl_xor(rs1, 8);
                const float iv1 = 1.f / rs1;
                float rs2 = 0.f;
                #pragma unroll
                for (int nt = 0; nt < 4; ++nt) {
                    const int n = nt * 16 + l15;
                    float e2 = (n < NTK) ? __expf(sc[mt][nt][r] * iv1) : 0.f;
                    sc[mt][nt][r] = e2;
                    rs2 += e2;
                }
                rs2 += __shfl_xor(rs2, 1); rs2 += __shfl_xor(rs2, 2);
                rs2 += __shfl_xor(rs2, 4); rs2 += __shfl_xor(rs2, 8);
                const float iv2 = 1.f / rs2;
                const int m = mt * 16 + g4 * 4 + r;
                #pragma unroll
                for (int nt = 0; nt < 4; ++nt)
                    Ph[m * 72 + nt * 16 + l15] = f2bf(sc[mt][nt][r] * iv2);
            }
        }

        fx4 oc[4][2];
        #pragma unroll
        for (int mt = 0; mt < 4; ++mt) { oc[mt][0] = (fx4){0.f,0.f,0.f,0.f}; oc[mt][1] = (fx4){0.f,0.f,0.f,0.f}; }
        #pragma unroll
        for (int ks = 0; ks < 2; ++ks) {
            s8v vb[2];
            #pragma unroll
            for (int nt = 0; nt < 2; ++nt) {
                union { s8v v; unsigned short u[8]; } pv;
                #pragma unroll
                for (int j = 0; j < 8; ++j) {
                    int tok = ks * 32 + g4 * 8 + j; if (tok > 48) tok = 48;
                    pv.u[j] = ovb[(size_t)(g0 + tok) * 96 + h * 32 + nt * 16 + l15];
                }
                vb[nt] = pv.v;
            }
            #pragma unroll
            for (int mt = 0; mt < 4; ++mt) {
                s8v pa = *reinterpret_cast<const s8v*>(&Ph[(mt * 16 + l15) * 72 + ks * 32 + g4 * 8]);
                oc[mt][0] = MFMA16(pa, vb[0], oc[mt][0]);
                oc[mt][1] = MFMA16(pa, vb[1], oc[mt][1]);
            }
        }
        #pragma unroll
        for (int mt = 0; mt < 4; ++mt) {
            #pragma unroll
            for (int r = 0; r < 4; ++r) {
                const int m = mt * 16 + g4 * 4 + r;
                if (m < NTK) {
                    ovb[(size_t)(g0 + m) * 96 + h * 32 + l15]      = f2bf(oc[mt][0][r]);
                    ovb[(size_t)(g0 + m) * 96 + h * 32 + 16 + l15] = f2bf(oc[mt][1][r]);
                }
            }
        }
    }
}

// ---------- K23: fused proj + residual + LN2 + MLP + residual, 32x32 MFMA ----------
// One wave owns 32 tokens: weight bytes AND MFMA instructions per token halve
// vs the 16x16 version, same single-accumulator structure. X2 held bf16 in LDS
// (43KB total -> 3 blocks/CU). D-layout: col=lane&31, row=(r&3)+8*(r>>2)+4*(lane>>5).
#define LDX2B 104
extern "C" __global__ void __launch_bounds__(256, 3) k23_fused(
    const unsigned short* __restrict__ ovb, const unsigned short* __restrict__ pwtf,
    const float* __restrict__ pb, const float* __restrict__ x,
    const float* __restrict__ g2, const float* __restrict__ b2,
    const unsigned short* __restrict__ w1f, const float* __restrict__ bf1,
    const unsigned short* __restrict__ w2f, const float* __restrict__ bf2,
    float* __restrict__ out)
{
    __shared__ unsigned short X2b[128 * LDX2B];  // 26624 B, wave-private rows
    __shared__ unsigned short Ac[128 * 64];      // 16384 B  (total 43008)
    const int tid = threadIdx.x, wave = tid >> 6, lane = tid & 63;
    const int l31 = lane & 31, gk = lane >> 5;
    const int row0 = blockIdx.x * 128 + wave * 32;   // orig-token rows

    // ---- proj (32x32): A-frags gathered from ovb via inverse shift map ----
    s8v a[6];
    {
        const int t = row0 + l31;
        const int b = t / (HH * WWI), rc = t - b * (HH * WWI);
        const int orr = rc / WWI, occ = rc - orr * WWI;
        int wr = orr + (HH - SHF); if (wr >= HH) wr -= HH;
        int wc = occ + (WWI - SHF); if (wc >= WWI) wc -= WWI;
        const int wtok = (b * 64 + (wr / WSZ) * 8 + (wc / WSZ)) * NTK
                         + (wr % WSZ) * WSZ + (wc % WSZ);
        const unsigned short* arow = ovb + (size_t)wtok * 96 + gk * 8;
        #pragma unroll
        for (int ks = 0; ks < 6; ++ks)
            a[ks] = *reinterpret_cast<const s8v*>(arow + ks * 16);
    }
    {
        fx16 acc[3];
        #pragma unroll
        for (int nt = 0; nt < 3; ++nt) acc[nt] = (fx16)(0.f);
        #pragma unroll
        for (int ks = 0; ks < 6; ++ks) {
            #pragma unroll
            for (int nt = 0; nt < 3; ++nt) {
                s8v b = *reinterpret_cast<const s8v*>(&pwtf[((nt * 6 + ks) * 64 + lane) * 8]);
                acc[nt] = MFMA32(a[ks], b, acc[nt]);
            }
        }
        // x2 = proj + pb + x -> LDS bf16 (D-layout indexing; x read linear-ish)
        #pragma unroll
        for (int nt = 0; nt < 3; ++nt) {
            const int col = nt * 32 + l31;
            const float pbc = pb[col];
            #pragma unroll
            for (int r = 0; r < 16; ++r) {
                const int drow = (r & 3) + 8 * (r >> 2) + 4 * gk;
                X2b[(wave * 32 + drow) * LDX2B + col] =
                    f2bf(acc[nt][r] + pbc + x[(size_t)(row0 + drow) * CC + col]);
            }
        }
    }

    // ---- LN2 from bf16 LDS (wave-private; 2 lanes share a row, xor-32 reduce) ----
    s8v ha[6];
    {
        const unsigned short* xr = &X2b[(wave * 32 + l31) * LDX2B + gk * 8];
        float h[48];
        float s = 0.f, s2 = 0.f;
        #pragma unroll
        for (int ks = 0; ks < 6; ++ks) {
            #pragma unroll
            for (int j = 0; j < 8; ++j) {
                float v = bf2f(xr[ks * 16 + j]);
                h[ks * 8 + j] = v;
                s += v; s2 = fmaf(v, v, s2);
            }
        }
        s += __shfl_xor(s, 32); s2 += __shfl_xor(s2, 32);
        const float mu = s * (1.f/CC);
        const float rs = rsqrtf(s2 * (1.f/CC) - mu * mu + LEPS);
        #pragma unroll
        for (int ks = 0; ks < 6; ++ks) {
            union { s8v v; unsigned short u[8]; } p;
            #pragma unroll
            for (int j = 0; j < 8; ++j) {
                int c = ks * 16 + gk * 8 + j;
                p.u[j] = f2bf((h[ks * 8 + j] - mu) * rs * g2[c] + b2[c]);
            }
            ha[ks] = p.v;
        }
    }

    fx16 oacc[3];
    #pragma unroll
    for (int nt = 0; nt < 3; ++nt) oacc[nt] = (fx16)(0.f);

    #pragma unroll 1
    for (int ck = 0; ck < 6; ++ck) {
        // fc1 (32x32): M=32 tok, N=64 (2 nt), K=96 (6 ks)
        fx16 a1[2];
        a1[0] = (fx16)(0.f); a1[1] = (fx16)(0.f);
        #pragma unroll
        for (int ks = 0; ks < 6; ++ks) {
            #pragma unroll
            for (int nt = 0; nt < 2; ++nt) {
                s8v b = *reinterpret_cast<const s8v*>(
                    &w1f[((((ck * 2 + nt) * 6) + ks) * 64 + lane) * 8]);
                a1[nt] = MFMA32(ha[ks], b, a1[nt]);
            }
        }
        // gelu^2 -> Ac (wave-private rows; in-wave lgkmcnt ordering)
        #pragma unroll
        for (int nt = 0; nt < 2; ++nt) {
            const float bb = bf1[ck * 64 + nt * 32 + l31];
            #pragma unroll
            for (int r = 0; r < 16; ++r) {
                const int drow = (r & 3) + 8 * (r >> 2) + 4 * gk;
                Ac[(wave * 32 + drow) * 64 + nt * 32 + l31] =
                    f2bf(gelu_t(gelu_t(a1[nt][r] + bb)));
            }
        }
        // fc2 (32x32): M=32 tok, N=96 (3 nt), K=64 (4 ks)
        #pragma unroll
        for (int ks = 0; ks < 4; ++ks) {
            s8v aa = *reinterpret_cast<const s8v*>(
                &Ac[(wave * 32 + l31) * 64 + ks * 16 + gk * 8]);
            #pragma unroll
            for (int nt = 0; nt < 3; ++nt) {
                s8v b = *reinterpret_cast<const s8v*>(
                    &w2f[((((ck * 3 + nt) * 4) + ks) * 64 + lane) * 8]);
                oacc[nt] = MFMA32(aa, b, oacc[nt]);
            }
        }
    }

    // ---- final: out = x2 + mlp + bf2 ----
    #pragma unroll
    for (int nt = 0; nt < 3; ++nt) {
        const int col = nt * 32 + l31;
        const float bb = bf2[col];
        #pragma unroll
        for (int r = 0; r < 16; ++r) {
            const int drow = (r & 3) + 8 * (r >> 2) + 4 * gk;
            out[(size_t)(row0 + drow) * CC + col] =
                bf2f(X2b[(wave * 32 + drow) * LDX2B + col]) + oacc[nt][r] + bb;
        }
    }
}

extern "C" void kernel_launch(void* const* d_in, const int* in_sizes, int n_in,
                              void* d_out, int out_size, void* d_ws, size_t ws_size,
                              hipStream_t stream)
{
    const float* x    = (const float*)d_in[0];
    const float* n1g  = (const float*)d_in[1];
    const float* n1b  = (const float*)d_in[2];
    const float* qw   = (const float*)d_in[3];
    const float* qb   = (const float*)d_in[4];
    const float* btab = (const float*)d_in[5];
    const float* pw   = (const float*)d_in[6];
    const float* pb   = (const float*)d_in[7];
    const float* n2g  = (const float*)d_in[8];
    const float* n2b  = (const float*)d_in[9];
    const float* w1   = (const float*)d_in[10];
    const float* bf1  = (const float*)d_in[11];
    const float* w2   = (const float*)d_in[12];
    const float* bf2  = (const float*)d_in[13];
    float* out = (float*)d_out;

    unsigned short* ovb  = (unsigned short*)d_ws;                 // TOT*96 bf16 = 19.3 MB (V then O)
    unsigned short* wbf  = ovb + (size_t)TOT * 96;
    unsigned short* qwtf = wbf;                                   // 27648 (16x16 frag)
    unsigned short* pwtf = qwtf + 27648;                          // 9216  (32x32 frag)
    unsigned short* w1f  = pwtf + 9216;                           // 36864 (32x32 frag)
    unsigned short* w2f  = w1f + 36864;                           // 36864 (32x32 frag)
    float* bmf = (float*)(wbf + 110592);                          // 49152 fp32 (D-frag)

    p0_prep  <<<624, 256, 0, stream>>>(qw, pw, w1, w2, btab, wbf);
    k12_fused<<<BB*NWIN, 256, 0, stream>>>(x, n1g, n1b, qwtf, qb, bmf, ovb);
    k23_fused<<<TOT/128, 256, 0, stream>>>(ovb, pwtf, pb, x, n2g, n2b,
                                           w1f, bf1, w2f, bf2, out);
}